// Round 2
// baseline (169.945 us; speedup 1.0000x reference)
//
#include <hip/hip_runtime.h>
#include <stdint.h>

// GRU: B=4096, T=128, I=16, H=64. Gate order r,z,n (PyTorch).
// Block = 16 batch rows, 4 waves. Wave w owns hidden cols [16w,16w+16) for all
// 3 gates (N-tiles w, w+4, w+8 of the per-step [16,64]@[64,192] MFMA GEMM).
// Split-bf16 (hi+lo) arithmetic for h and w_hh => near-fp32 accuracy.
// h fp32 master in registers; bf16 hi/lo staged in XOR-swizzled, double-buffered
// LDS for A-fragment reads. Weights resident in registers as B-fragments.

#define T_STEPS 128
#define NI 16
#define NH 64
#define RB 16

typedef float    f32x4  __attribute__((ext_vector_type(4)));
typedef uint32_t u32x4  __attribute__((ext_vector_type(4)));
typedef short    bf16x8 __attribute__((ext_vector_type(8)));  // MFMA operand (guide §3)
typedef __bf16   bfv8   __attribute__((ext_vector_type(8)));  // build-time view

static __device__ __forceinline__ uint32_t fbits(float f) { return __builtin_bit_cast(uint32_t, f); }
static __device__ __forceinline__ float    bitsf(uint32_t u) { return __builtin_bit_cast(float, u); }

static __device__ __forceinline__ float sigm_f(float x) {
  float e = __builtin_amdgcn_exp2f(-1.44269504f * x);   // v_exp_f32: e^-x
  return __builtin_amdgcn_rcpf(1.0f + e);               // v_rcp_f32
}
static __device__ __forceinline__ float tanh_f(float x) {
  float e = __builtin_amdgcn_exp2f(2.88539008f * x);    // e^(2x)
  return 1.0f - 2.0f * __builtin_amdgcn_rcpf(e + 1.0f);
}

// byte offset inside a [16 rows][64 cols] bf16 region (128B rows),
// 16B-chunk XOR swizzle by row (G4) so strided frag reads are ~2-way (free).
static __device__ __forceinline__ int h_addr(int row, int col) {
  return row * 128 + (((col >> 3) ^ (row & 7)) << 4) + ((col & 7) << 1);
}

static __device__ __forceinline__ bf16x8 ld_frag16(const unsigned char* p) {
  u32x4 v = *(const u32x4*)p;                           // ds_read_b128
  return __builtin_bit_cast(bf16x8, v);
}

#define MFMA(acc, a, b) acc = __builtin_amdgcn_mfma_f32_16x16x32_bf16(a, b, acc, 0, 0, 0)

__global__ __launch_bounds__(256)
void gru_fused(const float* __restrict__ x,
               const float* __restrict__ w_ih,
               const float* __restrict__ w_hh,
               const float* __restrict__ b_ih,
               const float* __restrict__ b_hh,
               const float* __restrict__ fc_w,
               const float* __restrict__ fc_b,
               float* __restrict__ out)
{
  __shared__ __align__(16) unsigned char sH[2][2][2048];  // [buf][hi/lo][16x64 bf16]
  __shared__ float s_red[4][16];

  const int tid  = threadIdx.x;
  const int lane = tid & 63;
  const int wv   = tid >> 6;       // wave 0..3
  const int colg = lane & 15;      // A-row (batch row) / col within 16-wide tile
  const int grp  = lane >> 4;      // lane group 0..3 (k-group)
  const int rb   = blockIdx.x * RB;
  const int hc   = wv * 16 + colg; // this lane's hidden-unit column (0..63)

  // zero h buffer 0 (h0 = 0)
  {
    uint32_t* p = (uint32_t*)&sH[0][0][0];
    #pragma unroll
    for (int i = 0; i < 4; ++i) p[tid + 256 * i] = 0u;
  }

  // ---- weight B-fragments (registers, loaded once) ----
  // B-frag mapping (m92-verified contiguous-k): lane holds B[k][n], n=lane&15,
  // k = grp*8 + j. Our B = w^T, so elem j = w[abs_col][k_global].
  bf16x8 bhi[3][2], blo[3][2], bx[3];
  #pragma unroll
  for (int g = 0; g < 3; ++g) {
    const float* wr = w_hh + (size_t)(g * 64 + hc) * NH + grp * 8;
    #pragma unroll
    for (int kt = 0; kt < 2; ++kt) {
      bfv8 vhi, vlo;
      #pragma unroll
      for (int j = 0; j < 8; ++j) {
        float w = wr[kt * 32 + j];
        __bf16 hi = (__bf16)w;                 // RNE
        vhi[j] = hi;
        vlo[j] = (__bf16)(w - (float)hi);
      }
      bhi[g][kt] = __builtin_bit_cast(bf16x8, vhi);
      blo[g][kt] = __builtin_bit_cast(bf16x8, vlo);
    }
    // x K-tile: k<16 pairs with x_hi, k>=16 pairs with x_lo; both halves use w_ih
    const float* wi = w_ih + (size_t)(g * 64 + hc) * NI + (grp & 1) * 8;
    bfv8 vx;
    #pragma unroll
    for (int j = 0; j < 8; ++j) vx[j] = (__bf16)wi[j];
    bx[g] = __builtin_bit_cast(bf16x8, vx);
  }

  const float bR  = b_ih[hc]       + b_hh[hc];
  const float bZ  = b_ih[64 + hc]  + b_hh[64 + hc];
  const float bNx = b_ih[128 + hc];            // n-gate: x and h parts separate
  const float bNh = b_hh[128 + hc];

  // per-lane x pointer: batch row rb+colg, 8 floats at (grp&1)*8
  const float* xp = x + (size_t)(rb + colg) * T_STEPS * NI + (grp & 1) * 8;

  const int a_off0 = h_addr(colg, 0 * 32 + grp * 8);  // A-frag LDS offsets (16B aligned)
  const int a_off1 = h_addr(colg, 1 * 32 + grp * 8);

  float hreg[4] = {0.f, 0.f, 0.f, 0.f};  // fp32 master h: rows grp*4+q, col hc

  f32x4 xa = *(const f32x4*)(xp);        // prefetch t=0
  f32x4 xb = *(const f32x4*)(xp + 4);

  const bool hi_grp = (grp < 2);

  __syncthreads();

  for (int t = 0; t < T_STEPS; ++t) {
    // prefetch next step's x
    const int tn = (t < T_STEPS - 1) ? (t + 1) : t;
    f32x4 xna = *(const f32x4*)(xp + (size_t)tn * NI);
    f32x4 xnb = *(const f32x4*)(xp + (size_t)tn * NI + 4);

    // A-fragment ds_reads for current h (issue early)
    const unsigned char* bh = &sH[t & 1][0][0];
    bf16x8 ah0 = ld_frag16(bh + a_off0);
    bf16x8 ah1 = ld_frag16(bh + a_off1);
    bf16x8 al0 = ld_frag16(bh + 2048 + a_off0);
    bf16x8 al1 = ld_frag16(bh + 2048 + a_off1);

    // build a_x fragment: groups 0,1 carry trunc-hi(x); groups 2,3 carry residual
    uint32_t d0, d1, d2, d3;
    {
      float v[8];
      #pragma unroll
      for (int j = 0; j < 4; ++j) {
        float x0 = xa[j], x1 = xb[j];
        float b0 = bitsf(fbits(x0) & 0xffff0000u);
        float b1 = bitsf(fbits(x1) & 0xffff0000u);
        v[j]     = hi_grp ? x0 : (x0 - b0);
        v[4 + j] = hi_grp ? x1 : (x1 - b1);
      }
      // pack high 16 bits of pairs: d = [hi16(v_even) | hi16(v_odd)<<16]
      d0 = __builtin_amdgcn_perm(fbits(v[1]), fbits(v[0]), 0x07060302u);
      d1 = __builtin_amdgcn_perm(fbits(v[3]), fbits(v[2]), 0x07060302u);
      d2 = __builtin_amdgcn_perm(fbits(v[5]), fbits(v[4]), 0x07060302u);
      d3 = __builtin_amdgcn_perm(fbits(v[7]), fbits(v[6]), 0x07060302u);
    }
    u32x4 axu = {d0, d1, d2, d3};
    bf16x8 ax = __builtin_bit_cast(bf16x8, axu);

    f32x4 aR  = {0.f, 0.f, 0.f, 0.f};
    f32x4 aZ  = {0.f, 0.f, 0.f, 0.f};
    f32x4 aNh = {0.f, 0.f, 0.f, 0.f};
    f32x4 aNx = {0.f, 0.f, 0.f, 0.f};

    // split-bf16: hi*hi + lo*hi + hi*lo ; x tile last (covers pack latency)
    MFMA(aR, ah0, bhi[0][0]); MFMA(aR, ah1, bhi[0][1]);
    MFMA(aR, al0, bhi[0][0]); MFMA(aR, al1, bhi[0][1]);
    MFMA(aR, ah0, blo[0][0]); MFMA(aR, ah1, blo[0][1]);
    MFMA(aR, ax, bx[0]);

    MFMA(aZ, ah0, bhi[1][0]); MFMA(aZ, ah1, bhi[1][1]);
    MFMA(aZ, al0, bhi[1][0]); MFMA(aZ, al1, bhi[1][1]);
    MFMA(aZ, ah0, blo[1][0]); MFMA(aZ, ah1, blo[1][1]);
    MFMA(aZ, ax, bx[1]);

    MFMA(aNh, ah0, bhi[2][0]); MFMA(aNh, ah1, bhi[2][1]);
    MFMA(aNh, al0, bhi[2][0]); MFMA(aNh, al1, bhi[2][1]);
    MFMA(aNh, ah0, blo[2][0]); MFMA(aNh, ah1, blo[2][1]);
    MFMA(aNx, ax, bx[2]);

    // gates + h update (lane-local), write bf16 hi/lo of h_new to other buffer
    unsigned char* bo = &sH[(t + 1) & 1][0][0];
    #pragma unroll
    for (int q = 0; q < 4; ++q) {
      float r = sigm_f(aR[q] + bR);
      float z = sigm_f(aZ[q] + bZ);
      float n = tanh_f(fmaf(r, aNh[q] + bNh, aNx[q] + bNx));
      float h = n + z * (hreg[q] - n);     // (1-z)*n + z*h
      hreg[q] = h;
      int off = h_addr(grp * 4 + q, hc);
      uint32_t u = fbits(h);
      float hif = bitsf(u & 0xffff0000u);
      *(uint16_t*)(bo + off)        = (uint16_t)(u >> 16);              // hi (trunc)
      *(uint16_t*)(bo + 2048 + off) = (uint16_t)(fbits(h - hif) >> 16); // lo
    }
    __syncthreads();
    xa = xna; xb = xnb;
  }

  // ---- head: pred[b] = sum_col h[b][col]*fc_w[col] + fc_b ----
  float fw = fc_w[hc];
  float v0 = hreg[0] * fw, v1 = hreg[1] * fw, v2 = hreg[2] * fw, v3 = hreg[3] * fw;
  #pragma unroll
  for (int off = 1; off < 16; off <<= 1) {   // reduce across the 16 cols in group
    v0 += __shfl_xor(v0, off, 64);
    v1 += __shfl_xor(v1, off, 64);
    v2 += __shfl_xor(v2, off, 64);
    v3 += __shfl_xor(v3, off, 64);
  }
  if (colg == 0) {
    s_red[wv][grp * 4 + 0] = v0;
    s_red[wv][grp * 4 + 1] = v1;
    s_red[wv][grp * 4 + 2] = v2;
    s_red[wv][grp * 4 + 3] = v3;
  }
  __syncthreads();
  if (tid < 16) {
    out[rb + tid] = s_red[0][tid] + s_red[1][tid] + s_red[2][tid] + s_red[3][tid] + fc_b[0];
  }
}

extern "C" void kernel_launch(void* const* d_in, const int* in_sizes, int n_in,
                              void* d_out, int out_size, void* d_ws, size_t ws_size,
                              hipStream_t stream) {
  (void)in_sizes; (void)n_in; (void)d_ws; (void)ws_size;
  const float* x    = (const float*)d_in[0];
  const float* w_ih = (const float*)d_in[1];
  const float* w_hh = (const float*)d_in[2];
  const float* b_ih = (const float*)d_in[3];
  const float* b_hh = (const float*)d_in[4];
  const float* fc_w = (const float*)d_in[5];
  const float* fc_b = (const float*)d_in[6];
  float* out = (float*)d_out;
  const int nblocks = out_size / RB;  // 4096/16 = 256 blocks, 1 per CU
  gru_fused<<<dim3(nblocks), dim3(256), 0, stream>>>(x, w_ih, w_hh, b_ih, b_hh,
                                                     fc_w, fc_b, out);
}